// Round 7
// baseline (93.187 us; speedup 1.0000x reference)
//
#include <hip/hip_runtime.h>

// v13: params in registers, broadcast via v_readlane (LDS-pipe cut #2).
// v12 post-mortem: occupancy doubling gave only -2.8 us -> latency was a
// minor term. Pipe census at v12: LDS ~2900 cyc/chunk/CU (128 frag b128 +
// 64 GEN b64 writes + 128 wave-uniform param b128) ~= 24 us of 38; VALU 15%,
// trans ~4 us, MFMA ~3 us. Params are 1/3 of LDS traffic. v9's global-param
// test was confounded (HBM latency on critical path + extra dispatch). v13:
// prologue computes per-(chunk,atom) params into per-lane registers (lane =
// 4c+j, two 3-reg sets cover 20 chunks); GEN broadcasts them with SGPR-
// indexed readlane (VALU pipe, idle) -- zero param LDS traffic, sG deleted
// (LDS 51.2 -> 40 KB), staging loop + 1 barrier deleted. Frag path, MFMA,
// epilogue, k_reduce unchanged from v12.

#define S 128
#define NS 32            // K-splits: 31 x 640 + 1 x 160 atoms
#define PER 640
#define BLOCK 1024       // 16 waves: tile = wav (r=wav>>2, c=wav&3)
#define KC 32            // atoms per chunk (2 MFMA K-steps)
#define GSTR 40          // f16 per position row: 32 atoms + 8 pad (80 B)

typedef _Float16 f16;
typedef _Float16 f16x2 __attribute__((ext_vector_type(2)));
typedef _Float16 f16x4 __attribute__((ext_vector_type(4)));
typedef _Float16 f16x8 __attribute__((ext_vector_type(8)));
typedef float floatx16 __attribute__((ext_vector_type(16)));

#if __has_builtin(__builtin_amdgcn_exp2f)
#define FAST_EXP2(x) __builtin_amdgcn_exp2f(x)
#else
#define FAST_EXP2(x) exp2f(x)
#endif
#if __has_builtin(__builtin_amdgcn_rcpf)
#define FAST_RCP(x) __builtin_amdgcn_rcpf(x)
#else
#define FAST_RCP(x) (1.0f / (x))
#endif

static __device__ __forceinline__ f16x2 PKRTZ(float a, float b) {
#if __has_builtin(__builtin_amdgcn_cvt_pkrtz)
    return __builtin_bit_cast(f16x2, __builtin_amdgcn_cvt_pkrtz(a, b));
#else
    return (f16x2){(f16)a, (f16)b};
#endif
}

static __device__ __forceinline__ float RDLANE(float v, int sl) {
    return __builtin_bit_cast(float,
        __builtin_amdgcn_readlane(__builtin_bit_cast(int, v), sl));
}

union frag_u { f16x8 v; f16x4 q[2]; f16x2 h[4]; };
union half4_u { f16x4 q; f16x2 h[2]; };

__global__ __launch_bounds__(BLOCK, 8) void k_proj(
    const float* __restrict__ mol,   // (B, A, 3)
    const float* __restrict__ stds,  // (A)
    const float* __restrict__ dens,  // (A)
    f16* __restrict__ part,          // (B*NS, 128*128) f16 partials, frag order
    int B, int A)
{
    __shared__ f16 g[2][2][S * GSTR];   // [parity][axis][pos*GSTR+atom]: 40 KB

    const int ks   = blockIdx.x;
    const int b    = blockIdx.y;
    const int tid  = threadIdx.x;
    const int lane = tid & 63;
    const int wav  = tid >> 6;       // 0..15 = output tile index (r*4 + c)
    const int l31  = lane & 31;
    const int hi   = lane >> 5;

    const int a0  = ks * PER;
    const int a1  = min(a0 + PER, A);
    const int cnt = a1 - a0;          // 640 or 160, both divisible by KC
    const int nc  = cnt >> 5;         // chunks of 32 atoms: 20 or 5

    // GEN role: wave -> (axis, 4-atom group); positions = lane, lane+64
    const int gaxis = wav >> 3;       // 0 = gx (cols), 1 = gy (rows)
    const int agrp  = wav & 7;        // 8 groups x 4 atoms = 32 atoms
    const float c0  = (float)lane - 63.5f;

    // compute role: tile (r = wav>>2, c = wav&3); frag rows/cols per lane
    const int arow = (wav >> 2) * 32 + l31;   // gy row
    const int bcol = (wav & 3) * 32 + l31;    // gx col
    const int koff = hi * 8;                  // K-step atom sub-offset

    // ---- per-lane param registers: lane 4c+j holds (mu, z, w) for chunk c,
    //      atom j of this wave's GEN assignment. Two sets: chunks 0-15, 16-19.
    float mu0, z0, w0, mu1, z1, w1;
    {
        auto LOADP = [&](int c, float& mu, float& z, float& w) {
            const int cc = min(c, nc - 1);
            const int a  = a0 + cc * KC + agrp * 4 + (lane & 3);
            const size_t idx = (size_t)b * A + a;
            float mx = mol[idx * 3 + 0];
            float my = mol[idx * 3 + 1];
            float v  = stds[a] * stds[a];
            float rv = FAST_RCP(v);
            z  = -0.72134752044448f * rv;                 // -0.5*log2(e)/var
            w  = gaxis ? __log2f(dens[a] * 0.15915494309189535f * rv) : 0.0f;
            mu = gaxis ? my : mx;
        };
        LOADP(lane >> 2,        mu0, z0, w0);
        LOADP(16 + (lane >> 2), mu1, z1, w1);
    }

    floatx16 acc = (floatx16){0.f};

    // broadcast params for (chunk-local atom sl) from the given register set
    auto GEN_FROM = [&](float muR, float zR, float wR, int lb,
                        half4_u& V0, half4_u& V1) {
#pragma unroll
        for (int i2 = 0; i2 < 2; ++i2) {
            float e0[2], e1[2];
#pragma unroll
            for (int u = 0; u < 2; ++u) {
                const int sl = lb + i2 * 2 + u;   // uniform lane index
                float mu = RDLANE(muR, sl);
                float z  = RDLANE(zR,  sl);
                float w  = RDLANE(wR,  sl);
                float d  = c0 - mu;
                float t  = z * d;
                float g0 = fmaf(t, d, w);
                float g1 = fmaf(128.0f, t, fmaf(4096.0f, z, g0));  // pos +64
                e0[u] = FAST_EXP2(g0);
                e1[u] = FAST_EXP2(g1);
            }
            V0.h[i2] = PKRTZ(e0[0], e0[1]);
            V1.h[i2] = PKRTZ(e1[0], e1[1]);
        }
    };
    auto GEN_COMPUTE = [&](int c, half4_u& V0, half4_u& V1) {
        if (c < 16) GEN_FROM(mu0, z0, w0, c * 4, V0, V1);
        else        GEN_FROM(mu1, z1, w1, (c - 16) * 4, V0, V1);
    };

    // STEP: consume chunk c from parity P; generate chunk c+1 into P^1.
    // P^1 was fully consumed before the previous barrier -> safe pre-barrier.
#define STEP(P)                                                                \
    do {                                                                       \
        const f16* gy = g[(P)][1];                                             \
        const f16* gx = g[(P)][0];                                             \
        const bool gen = (c + 1 < nc);                                         \
        half4_u V0, V1;                                                        \
        if (gen) GEN_COMPUTE(c + 1, V0, V1);                                   \
        _Pragma("unroll")                                                      \
        for (int s = 0; s < 2; ++s) {                                          \
            frag_u Af, Bf;                                                     \
            Af.v = *(const f16x8*)(gy + arow * GSTR + s * 16 + koff);          \
            Bf.v = *(const f16x8*)(gx + bcol * GSTR + s * 16 + koff);          \
            acc = __builtin_amdgcn_mfma_f32_32x32x16_f16(Af.v, Bf.v, acc, 0, 0, 0); \
        }                                                                      \
        if (gen) {                                                             \
            f16* dst = &g[(P) ^ 1][gaxis][lane * GSTR + agrp * 4];             \
            *(f16x4*)dst               = V0.q;                                 \
            *(f16x4*)(dst + 64 * GSTR) = V1.q;                                 \
        }                                                                      \
        __syncthreads();                                                       \
        ++c;                                                                   \
    } while (0)

    {   // prologue: chunk 0 into parity 0
        half4_u V0, V1;
        GEN_COMPUTE(0, V0, V1);
        f16* dst = &g[0][gaxis][lane * GSTR + agrp * 4];
        *(f16x4*)dst               = V0.q;
        *(f16x4*)(dst + 64 * GSTR) = V1.q;
    }
    __syncthreads();

    int c = 0;
    while (c + 2 <= nc) { STEP(0); STEP(1); }
    if (c < nc) STEP(0);              // nc odd (tail split): even parity
#undef STEP

    // epilogue: direct store -- wave owns tile wav completely (full K summed)
    {
        f16* pq = part + ((size_t)(b * NS + ks)) * (S * S)
                       + (size_t)wav * 1024 + lane * 16;
        frag_u lo, hiv;
#pragma unroll
        for (int jp = 0; jp < 4; ++jp) {
            lo.h[jp]  = PKRTZ(acc[2 * jp],     acc[2 * jp + 1]);
            hiv.h[jp] = PKRTZ(acc[2 * jp + 8], acc[2 * jp + 9]);
        }
        *(f16x8*)(pq + 0) = lo.v;
        *(f16x8*)(pq + 8) = hiv.v;
    }
}

// sum NS f16 partials per batch: 4 waves/block each sum 8 slices (512 blocks),
// LDS combine, un-permute fragment order, write f32.
__global__ __launch_bounds__(256) void k_reduce(const f16* __restrict__ part,
                                                float* __restrict__ out) {
    __shared__ float lred[3][64][9];   // +1 pad: conflict-free strided stores
    const int b    = blockIdx.z;
    const int lane = threadIdx.x & 63;
    const int w    = threadIdx.x >> 6;
    const int f8   = (blockIdx.x * 64 + lane) * 8;   // frag-order base idx

    const f16* src = part + (size_t)b * NS * (S * S) + (size_t)(w * 8) * (S * S) + f8;
    float s[8] = {0.f};
#pragma unroll
    for (int t = 0; t < 8; ++t) {
        f16x8 v = *(const f16x8*)&src[(size_t)t * (S * S)];
#pragma unroll
        for (int i = 0; i < 8; ++i) s[i] += (float)v[i];
    }

    if (w) {
#pragma unroll
        for (int i = 0; i < 8; ++i) lred[w - 1][lane][i] = s[i];
    }
    __syncthreads();

    if (w == 0) {
#pragma unroll
        for (int j = 0; j < 3; ++j)
#pragma unroll
            for (int i = 0; i < 8; ++i) s[i] += lred[j][lane][i];

        // decode f8 = tile*1024 + lane_f*16 + reg0; tile = r*4 + c (32x32 tiles)
        const int reg0   = f8 & 15;
        const int lane_f = (f8 >> 4) & 63;
        const int tile   = f8 >> 10;
        const int r      = tile >> 2;
        const int cc     = tile & 3;
        // mfma_32x32 C/D: col = lane&31, row = (reg&3) + 8*(reg>>2) + 4*(lane>>5)
        const int rowb = r * 32 + 4 * (lane_f >> 5);
        const int col  = cc * 32 + (lane_f & 31);
#pragma unroll
        for (int i = 0; i < 8; ++i) {
            const int reg = reg0 + i;
            const int row = rowb + (reg & 3) + 8 * (reg >> 2);
            out[((size_t)b * S + row) * S + col] = s[i];
        }
    }
}

extern "C" void kernel_launch(void* const* d_in, const int* in_sizes, int n_in,
                              void* d_out, int out_size, void* d_ws, size_t ws_size,
                              hipStream_t stream) {
    const float* mol  = (const float*)d_in[0];
    const float* stds = (const float*)d_in[1];
    const float* dens = (const float*)d_in[2];
    float* out = (float*)d_out;

    const int A = in_sizes[1];             // 20000
    const int B = in_sizes[0] / (A * 3);   // 16

    f16* part = (f16*)d_ws;                // B*NS*16384*2 = 16 MB

    k_proj<<<dim3(NS, B), dim3(BLOCK), 0, stream>>>(mol, stds, dens, part, B, A);
    k_reduce<<<dim3((S * S) / (64 * 8), 1, B), dim3(256), 0, stream>>>(part, out);
}

// Round 8
// 88.025 us; speedup vs baseline: 1.0586x; 1.0586x over previous
//
#include <hip/hip_runtime.h>

// v14: v12 structure + conflict-free LDS geometry (v11's GSTR=68, b64 ops).
// v13 post-mortem: readlane broadcast regressed (serialized VALU->SGPR chain
// on the exp critical path + uncoalesced per-wave param gather) -- implement-
// ation failure, not theory failure. v12's GSTR=40 (20-dword stride) makes
// every ds_read_b128 frag read a 4-way bank conflict (lanes i,i+8,i+16,i+24
// share a bank quad; 1.58x per m136) -- and 16B-aligned padding can't beat
// 4-way for b128. v11's GSTR=68 (34 dwords, gcd(34,32)=2 -> 2-way = free)
// was neutral at 4 waves/SIMD (latency regime hid conflicts); v12's 8
// waves/SIMD doubled LDS pressure -> regime is now LDS-throughput-bound, so
// the fix should pay. 64-atom parity chunks (barriers 21->11), b64 LDS ops,
// tail padded with zero-weight params. LDS 79,872 B -> 2 blocks/CU held.

#define S 128
#define NS 32            // K-splits: 31 x 640 + 1 x 160 atoms
#define PER 640
#define BLOCK 1024       // 16 waves: tile = wav (r=wav>>2, c=wav&3)
#define KC 64            // atoms per chunk (4 MFMA K-steps)
#define GSTR 68          // f16 per position row: 64 atoms + 4 pad (136 B)

typedef _Float16 f16;
typedef _Float16 f16x2 __attribute__((ext_vector_type(2)));
typedef _Float16 f16x4 __attribute__((ext_vector_type(4)));
typedef _Float16 f16x8 __attribute__((ext_vector_type(8)));
typedef float floatx16 __attribute__((ext_vector_type(16)));

#if __has_builtin(__builtin_amdgcn_exp2f)
#define FAST_EXP2(x) __builtin_amdgcn_exp2f(x)
#else
#define FAST_EXP2(x) exp2f(x)
#endif
#if __has_builtin(__builtin_amdgcn_rcpf)
#define FAST_RCP(x) __builtin_amdgcn_rcpf(x)
#else
#define FAST_RCP(x) (1.0f / (x))
#endif

static __device__ __forceinline__ f16x2 PKRTZ(float a, float b) {
#if __has_builtin(__builtin_amdgcn_cvt_pkrtz)
    return __builtin_bit_cast(f16x2, __builtin_amdgcn_cvt_pkrtz(a, b));
#else
    return (f16x2){(f16)a, (f16)b};
#endif
}

union frag_u { f16x8 v; f16x4 q[2]; f16x2 h[4]; };
union half4_u { f16x4 q; f16x2 h[2]; };

struct SharedT {
    float4 sG[PER];              // (x, y, z, w): 10,240 B
    f16 g[2][2][S * GSTR];       // [parity][axis][pos*GSTR + atom]: 69,632 B
};                               // 79,872 B -> 2 blocks/CU, 32 waves/CU

__global__ __launch_bounds__(BLOCK, 8) void k_proj(
    const float* __restrict__ mol,   // (B, A, 3)
    const float* __restrict__ stds,  // (A)
    const float* __restrict__ dens,  // (A)
    f16* __restrict__ part,          // (B*NS, 128*128) f16 partials, frag order
    int B, int A)
{
    __shared__ SharedT sh;

    const int ks   = blockIdx.x;
    const int b    = blockIdx.y;
    const int tid  = threadIdx.x;
    const int lane = tid & 63;
    const int wav  = tid >> 6;       // 0..15 = output tile index (r*4 + c)
    const int l31  = lane & 31;
    const int hi   = lane >> 5;

    const int a0   = ks * PER;
    const int a1   = min(a0 + PER, A);
    const int cnt  = a1 - a0;               // 640 or 160
    const int cntp = (cnt + KC - 1) & ~(KC - 1);  // padded: 640 or 192
    const int nc   = cntp >> 6;             // 64-atom chunks: 10 or 3

    for (int i = tid; i < cntp; i += BLOCK) {
        const int a = a0 + i;
        if (a < a1) {
            const size_t idx = (size_t)b * A + a;
            float x  = mol[idx * 3 + 0];
            float y  = mol[idx * 3 + 1];
            float v  = stds[a] * stds[a];
            float rv = FAST_RCP(v);
            float z  = -0.72134752044448f * rv;             // -0.5*log2(e)/var
            float w  = __log2f(dens[a] * 0.15915494309189535f * rv);
            sh.sG[i] = make_float4(x, y, z, w);
        } else {
            // dummy atom: gy = exp2(-1e4) = 0 -> zero contribution
            sh.sG[i] = make_float4(0.f, 0.f, 0.f, -10000.f);
        }
    }
    __syncthreads();

    // GEN role: wave -> (axis, 8-atom group); positions = lane, lane+64
    const int gaxis = wav >> 3;       // 0 = gx (cols), 1 = gy (rows)
    const int agrp  = wav & 7;        // 8 groups x 8 atoms = 64 atoms
    const float c0  = (float)lane - 63.5f;

    // compute role: tile (r = wav>>2, c = wav&3); frag rows/cols per lane
    const int arow = (wav >> 2) * 32 + l31;   // gy row
    const int bcol = (wav & 3) * 32 + l31;    // gx col
    const int koff = hi * 8;                  // K-step atom sub-offset

    floatx16 acc = (floatx16){0.f};

    // 4 atoms (half of this wave's 8) -> 2 positions, packed halves
    auto GEN_HALF = [&](const float4* prm, half4_u& V0, half4_u& V1) {
#pragma unroll
        for (int i2 = 0; i2 < 2; ++i2) {
            float e0[2], e1[2];
#pragma unroll
            for (int u = 0; u < 2; ++u) {
                float4 p = prm[i2 * 2 + u];      // (x, y, z, w)
                float mu = gaxis ? p.y : p.x;
                float wc = gaxis ? p.w : 0.0f;   // gx carries no coef
                float d  = c0 - mu;
                float t  = p.z * d;
                float g0 = fmaf(t, d, wc);
                float g1 = fmaf(128.0f, t, fmaf(4096.0f, p.z, g0));  // pos +64
                e0[u] = FAST_EXP2(g0);
                e1[u] = FAST_EXP2(g1);
            }
            V0.h[i2] = PKRTZ(e0[0], e0[1]);
            V1.h[i2] = PKRTZ(e1[0], e1[1]);
        }
    };

    // generate + write this wave's 8 atoms of chunk c into parity par.
    // dst byte = 136*lane + 16*agrp (8B-aligned) -> b64 stores, 2-way banks.
    auto GEN_CHUNK = [&](int c, int par) {
        const float4* prm = &sh.sG[c * KC + agrp * 8];   // wave-uniform bcast
        f16* dst  = &sh.g[par][gaxis][lane * GSTR + agrp * 8];
        f16* dst2 = dst + 64 * GSTR;                     // pos = lane + 64
        half4_u V0, V1;
        GEN_HALF(prm, V0, V1);                           // atoms 0-3
        *(f16x4*)(dst)      = V0.q;
        *(f16x4*)(dst2)     = V1.q;
        GEN_HALF(prm + 4, V0, V1);                       // atoms 4-7
        *(f16x4*)(dst + 4)  = V0.q;
        *(f16x4*)(dst2 + 4) = V1.q;
    };

    // STEP: consume chunk c (64 atoms = 4 K-steps) from parity P; generate
    // chunk c+1 into P^1 (fully consumed before the previous barrier).
#define STEP(P)                                                                \
    do {                                                                       \
        const f16* gy = sh.g[(P)][1];                                          \
        const f16* gx = sh.g[(P)][0];                                          \
        const bool gen = (c + 1 < nc);                                         \
        if (gen) GEN_CHUNK(c + 1, (P) ^ 1);                                    \
        _Pragma("unroll")                                                      \
        for (int s = 0; s < 4; ++s) {                                          \
            frag_u Af, Bf;                                                     \
            const f16* ay = gy + arow * GSTR + s * 16 + koff;                  \
            const f16* bx = gx + bcol * GSTR + s * 16 + koff;                  \
            Af.q[0] = *(const f16x4*)(ay);                                     \
            Af.q[1] = *(const f16x4*)(ay + 4);                                 \
            Bf.q[0] = *(const f16x4*)(bx);                                     \
            Bf.q[1] = *(const f16x4*)(bx + 4);                                 \
            acc = __builtin_amdgcn_mfma_f32_32x32x16_f16(Af.v, Bf.v, acc, 0, 0, 0); \
        }                                                                      \
        __syncthreads();                                                       \
        ++c;                                                                   \
    } while (0)

    GEN_CHUNK(0, 0);                  // prologue: chunk 0 into parity 0
    __syncthreads();

    int c = 0;
    while (c + 2 <= nc) { STEP(0); STEP(1); }
    if (c < nc) STEP(0);              // nc odd: last chunk is even parity
#undef STEP

    // epilogue: direct store -- wave owns tile wav completely (full K summed)
    {
        f16* pq = part + ((size_t)(b * NS + ks)) * (S * S)
                       + (size_t)wav * 1024 + lane * 16;
        frag_u lo, hiv;
#pragma unroll
        for (int jp = 0; jp < 4; ++jp) {
            lo.h[jp]  = PKRTZ(acc[2 * jp],     acc[2 * jp + 1]);
            hiv.h[jp] = PKRTZ(acc[2 * jp + 8], acc[2 * jp + 9]);
        }
        *(f16x8*)(pq + 0) = lo.v;
        *(f16x8*)(pq + 8) = hiv.v;
    }
}

// sum NS f16 partials per batch: 4 waves/block each sum 8 slices (512 blocks),
// LDS combine, un-permute fragment order, write f32.
__global__ __launch_bounds__(256) void k_reduce(const f16* __restrict__ part,
                                                float* __restrict__ out) {
    __shared__ float lred[3][64][9];   // +1 pad: conflict-free strided stores
    const int b    = blockIdx.z;
    const int lane = threadIdx.x & 63;
    const int w    = threadIdx.x >> 6;
    const int f8   = (blockIdx.x * 64 + lane) * 8;   // frag-order base idx

    const f16* src = part + (size_t)b * NS * (S * S) + (size_t)(w * 8) * (S * S) + f8;
    float s[8] = {0.f};
#pragma unroll
    for (int t = 0; t < 8; ++t) {
        f16x8 v = *(const f16x8*)&src[(size_t)t * (S * S)];
#pragma unroll
        for (int i = 0; i < 8; ++i) s[i] += (float)v[i];
    }

    if (w) {
#pragma unroll
        for (int i = 0; i < 8; ++i) lred[w - 1][lane][i] = s[i];
    }
    __syncthreads();

    if (w == 0) {
#pragma unroll
        for (int j = 0; j < 3; ++j)
#pragma unroll
            for (int i = 0; i < 8; ++i) s[i] += lred[j][lane][i];

        // decode f8 = tile*1024 + lane_f*16 + reg0; tile = r*4 + c (32x32 tiles)
        const int reg0   = f8 & 15;
        const int lane_f = (f8 >> 4) & 63;
        const int tile   = f8 >> 10;
        const int r      = tile >> 2;
        const int cc     = tile & 3;
        // mfma_32x32 C/D: col = lane&31, row = (reg&3) + 8*(reg>>2) + 4*(lane>>5)
        const int rowb = r * 32 + 4 * (lane_f >> 5);
        const int col  = cc * 32 + (lane_f & 31);
#pragma unroll
        for (int i = 0; i < 8; ++i) {
            const int reg = reg0 + i;
            const int row = rowb + (reg & 3) + 8 * (reg >> 2);
            out[((size_t)b * S + row) * S + col] = s[i];
        }
    }
}

extern "C" void kernel_launch(void* const* d_in, const int* in_sizes, int n_in,
                              void* d_out, int out_size, void* d_ws, size_t ws_size,
                              hipStream_t stream) {
    const float* mol  = (const float*)d_in[0];
    const float* stds = (const float*)d_in[1];
    const float* dens = (const float*)d_in[2];
    float* out = (float*)d_out;

    const int A = in_sizes[1];             // 20000
    const int B = in_sizes[0] / (A * 3);   // 16

    f16* part = (f16*)d_ws;                // B*NS*16384*2 = 16 MB

    k_proj<<<dim3(NS, B), dim3(BLOCK), 0, stream>>>(mol, stds, dens, part, B, A);
    k_reduce<<<dim3((S * S) / (64 * 8), 1, B), dim3(256), 0, stream>>>(part, out);
}